// Round 28
// baseline (201.932 us; speedup 1.0000x reference)
//
#include <hip/hip_runtime.h>
#include <math.h>

// Problem constants (from reference)
#define BB   8      // batch
#define MM   4      // MAXM
#define DD   128    // DIM
#define NHH  8      // heads
#define QDD  16     // head dim
#define NN   256    // H*W
#define KO   128    // NH*QD
#define DTILE 8     // D-rows per out_kernel block

typedef float v2f __attribute__((ext_vector_type(2)));
#define PKFMA(a, b, c) __builtin_elementwise_fma((a), (b), (c))

typedef __attribute__((ext_vector_type(8))) short bf16x8;   // 8 bf16 (4 VGPR)
typedef __attribute__((ext_vector_type(4))) float f32x4;    // MFMA acc

__device__ inline unsigned short f2bf(float f) {            // RNE float->bf16
    union { float f; unsigned u; } v; v.f = f;
    unsigned r = v.u + 0x7FFF + ((v.u >> 16) & 1);
    return (unsigned short)(r >> 16);
}
__device__ inline float bf2f(unsigned short h) {
    union { unsigned u; float f; } v; v.u = ((unsigned)h) << 16;
    return v.f;
}
// split x = hi + lo (both bf16); returns packed pair
__device__ inline void bfsplit(float x, unsigned short& hi, unsigned short& lo) {
    hi = f2bf(x);
    lo = f2bf(x - bf2f(hi));
}

// ---------------------------------------------------------------------------
// Kernel 0 (trig-free): pe[m,i,j] = exp(i*m*theta) = ((dx+i*dy)/r)^m.
// ---------------------------------------------------------------------------
__global__ void pe_kernel(float2* __restrict__ peIJ, float2* __restrict__ peT) {
    int bid = blockIdx.x;           // m*N + i
    int m = bid >> 8;
    int i = bid & 255;
    int j = threadIdx.x;
    float dy = (float)((j >> 4) - (i >> 4));
    float dx = (float)((j & 15) - (i & 15));
    float r2 = dx * dx + dy * dy;
    float c1 = 1.f, s1 = 0.f;
    if (r2 > 0.f) {
        float rinv = rsqrtf(r2);
        c1 = dx * rinv; s1 = dy * rinv;
    }
    float c = 1.f, s = 0.f;
    for (int k = 0; k < m; ++k) {   // m is block-uniform (0..3)
        float nc = c * c1 - s * s1;
        s = c * s1 + s * c1;
        c = nc;
    }
    peIJ[(m * NN + i) * NN + j] = make_float2(c, s);
    peT[(m * NN + j) * NN + i] = make_float2(c, s);
}

// ---------------------------------------------------------------------------
// Kernel 1a: convA — emb -> A' split-bf16. uint idx = tmh*2048 + q*128 + D;
// low short = k=2D (ar), high short = k=2D+1 (ai).
// ---------------------------------------------------------------------------
__global__ void convA_kernel(const float* __restrict__ er, const float* __restrict__ ei,
                             unsigned int* __restrict__ AbfHi, unsigned int* __restrict__ AbfLo) {
    int tmh = blockIdx.x;                 // 0..95
    int base = tmh * QDD * DD;
#pragma unroll
    for (int it = 0; it < 8; ++it) {
        int idx = threadIdx.x + it * 256;  // q*128+D
        float ar = er[base + idx];
        float ai = ei[base + idx];
        unsigned short arh, arl, aih, ail;
        bfsplit(ar, arh, arl);
        bfsplit(ai, aih, ail);
        AbfHi[base + idx] = (unsigned int)arh | ((unsigned int)aih << 16);
        AbfLo[base + idx] = (unsigned int)arl | ((unsigned int)ail << 16);
    }
}

// ---------------------------------------------------------------------------
// Kernel 1b: convB — x -> split-bf16 B bufs, k-fastest [32 bm][256 n][128 D]u.
// Bre shorts: [n][2D]=br, [2D+1]=-bi ; Bim: [2D]=bi, [2D+1]=br.
// ---------------------------------------------------------------------------
__global__ void convB_kernel(const float* __restrict__ xr, const float* __restrict__ xi,
                             unsigned int* __restrict__ BreHi, unsigned int* __restrict__ BreLo,
                             unsigned int* __restrict__ BimHi, unsigned int* __restrict__ BimLo) {
    int bid = blockIdx.x;                 // 256 = 32 bm x 8 Dg
    int bm = bid >> 3;
    int Dg = bid & 7;
    int D0 = Dg * 16;
    int tid = threadIdx.x;

    __shared__ float sxr[16][257];
    __shared__ float sxi[16][257];

    const float* xrp = xr + (size_t)bm * DD * NN;
    const float* xip = xi + (size_t)bm * DD * NN;
#pragma unroll
    for (int it = 0; it < 16; ++it) {
        int i2 = tid + it * 256;
        int r = i2 >> 8, c = i2 & 255;
        sxr[r][c] = xrp[(size_t)(D0 + r) * NN + c];
        sxi[r][c] = xip[(size_t)(D0 + r) * NN + c];
    }
    __syncthreads();

    int n = tid;
    unsigned int reh[16], rel_[16], imh[16], iml[16];
#pragma unroll
    for (int d = 0; d < 16; ++d) {
        float br = sxr[d][n];
        float bi = sxi[d][n];
        unsigned short brh, brl, bih, bil, nbh, nbl;
        bfsplit(br, brh, brl);
        bfsplit(bi, bih, bil);
        nbh = bih ^ 0x8000; nbl = bil ^ 0x8000;   // -bi (exact negation of both halves)
        reh[d]  = (unsigned int)brh | ((unsigned int)nbh << 16);
        rel_[d] = (unsigned int)brl | ((unsigned int)nbl << 16);
        imh[d]  = (unsigned int)bih | ((unsigned int)brh << 16);
        iml[d]  = (unsigned int)bil | ((unsigned int)brl << 16);
    }
    size_t ob = (size_t)bm * 32768 + (size_t)n * 128 + D0;
#pragma unroll
    for (int w = 0; w < 4; ++w) {
        ((uint4*)(BreHi + ob))[w] = make_uint4(reh[4*w], reh[4*w+1], reh[4*w+2], reh[4*w+3]);
        ((uint4*)(BreLo + ob))[w] = make_uint4(rel_[4*w], rel_[4*w+1], rel_[4*w+2], rel_[4*w+3]);
        ((uint4*)(BimHi + ob))[w] = make_uint4(imh[4*w], imh[4*w+1], imh[4*w+2], imh[4*w+3]);
        ((uint4*)(BimLo + ob))[w] = make_uint4(iml[4*w], iml[4*w+1], iml[4*w+2], iml[4*w+3]);
    }
}

// ---------------------------------------------------------------------------
// Kernel 1c (MFMA, split-bf16): E = A'·B via 16x16x32 bf16 MFMA, fp32 acc.
// Products: Hi·Hi + Hi·Lo + Lo·Hi  (Lo·Lo ~2^-18, dropped).
// ---------------------------------------------------------------------------
__global__ __launch_bounds__(256)
void e_mfma_kernel(const unsigned short* __restrict__ AbfHi,
                   const unsigned short* __restrict__ AbfLo,
                   const unsigned short* __restrict__ BreHi,
                   const unsigned short* __restrict__ BreLo,
                   const unsigned short* __restrict__ BimHi,
                   const unsigned short* __restrict__ BimLo,
                   float2* __restrict__ E) {
    int bid = blockIdx.x;
    int xcd = bid & 7;
    int idx = bid >> 3;                   // 0..95
    int pair = xcd * 4 + (idx & 3);       // b*MM+m (XCD-pinned: B panels L2-resident)
    int th  = idx >> 2;                   // 0..23 = t*NHH+h
    int t = th >> 3, h = th & 7;
    int b = pair >> 2, m = pair & 3;
    int tid = threadIdx.x;
    int wav = tid >> 6, lane = tid & 63;
    int lo = lane & 15, hi = lane >> 4;

    size_t aoff = ((size_t)((t * MM + m) * NHH + h)) * QDD * 256;
    const unsigned short* AHp = AbfHi + aoff;
    const unsigned short* ALp = AbfLo + aoff;
    size_t boff = (size_t)pair * 256 * 256;
    const unsigned short* BrH = BreHi + boff;
    const unsigned short* BrL = BreLo + boff;
    const unsigned short* BiH = BimHi + boff;
    const unsigned short* BiL = BimLo + boff;

    f32x4 accRe[4], accIm[4];
#pragma unroll
    for (int nt = 0; nt < 4; ++nt) { accRe[nt] = (f32x4)(0.f); accIm[nt] = (f32x4)(0.f); }

#pragma unroll
    for (int ks = 0; ks < 8; ++ks) {
        int k0 = ks * 32;
        int arow = lo * 256 + k0 + hi * 8;
        bf16x8 aH = *(const bf16x8*)(AHp + arow);
        bf16x8 aL = *(const bf16x8*)(ALp + arow);
#pragma unroll
        for (int nt = 0; nt < 4; ++nt) {
            int n0 = (wav * 4 + nt) * 16;
            size_t brow = (size_t)(n0 + lo) * 256 + k0 + hi * 8;
            bf16x8 brh = *(const bf16x8*)(BrH + brow);
            bf16x8 brl = *(const bf16x8*)(BrL + brow);
            bf16x8 bih = *(const bf16x8*)(BiH + brow);
            bf16x8 bil = *(const bf16x8*)(BiL + brow);
            accRe[nt] = __builtin_amdgcn_mfma_f32_16x16x32_bf16(aH, brh, accRe[nt], 0, 0, 0);
            accRe[nt] = __builtin_amdgcn_mfma_f32_16x16x32_bf16(aH, brl, accRe[nt], 0, 0, 0);
            accRe[nt] = __builtin_amdgcn_mfma_f32_16x16x32_bf16(aL, brh, accRe[nt], 0, 0, 0);
            accIm[nt] = __builtin_amdgcn_mfma_f32_16x16x32_bf16(aH, bih, accIm[nt], 0, 0, 0);
            accIm[nt] = __builtin_amdgcn_mfma_f32_16x16x32_bf16(aH, bil, accIm[nt], 0, 0, 0);
            accIm[nt] = __builtin_amdgcn_mfma_f32_16x16x32_bf16(aL, bih, accIm[nt], 0, 0, 0);
        }
    }

    size_t ebase = (size_t)((((t * BB + b) * MM + m) * NHH + h) * QDD) * NN;
#pragma unroll
    for (int nt = 0; nt < 4; ++nt) {
        int n0 = (wav * 4 + nt) * 16;
#pragma unroll
        for (int reg = 0; reg < 4; ++reg) {
            int q = hi * 4 + reg;
            E[ebase + (size_t)q * NN + n0 + lo] = make_float2(accRe[nt][reg], accIm[nt][reg]);
        }
    }
}

// ---------------------------------------------------------------------------
// Kernel 2: QE[b,m,h,i] = sum_q conj(E0[b,m,h,q,i]) * enc0[m,h,q]
// ---------------------------------------------------------------------------
__global__ void qe_kernel(const float2* __restrict__ E,
                          const float* __restrict__ encr, const float* __restrict__ enci,
                          float2* __restrict__ QE) {
    int bid = blockIdx.x;                 // (b*MM+m)*NHH + h
    int i = threadIdx.x;
    const float2* e0 = E + (size_t)(bid) * QDD * NN;   // t=0 plane
    int h = bid & 7;
    int bm = bid >> 3;
    int m = bm & 3;
    int encbase = (m * NHH + h) * QDD;    // enc[0,m,h,0,q,0]
    float ar = 0.f, ai = 0.f;
#pragma unroll
    for (int q = 0; q < QDD; ++q) {
        float2 e = e0[q * NN + i];
        float cr = encr[encbase + q], ci = enci[encbase + q];
        // conj(e) * enc
        ar = fmaf(e.x, cr, fmaf( e.y, ci, ar));
        ai = fmaf(e.x, ci, fmaf(-e.y, cr, ai));
    }
    QE[(size_t)bid * NN + i] = make_float2(ar, ai);
}

// ---------------------------------------------------------------------------
// Kernel 3 (v4): A[b,h,i,j]; 512 thr = 2 itiles x 256 j; shared sk staging.
// ---------------------------------------------------------------------------
__global__ __launch_bounds__(512)
void a_kernel(const float2* __restrict__ E, const float2* __restrict__ QE,
              const float2* __restrict__ peIJ, float2* __restrict__ A) {
    int bid = blockIdx.x;                 // 512 blocks = 8 xcd x 64 idx
    int xcd = bid & 7;
    int idx = bid >> 3;                   // 0..63
    int bh = xcd * 8 + (idx & 7);         // b*NHH+h, 0..63
    int ipair = idx >> 3;                 // 0..7 (pair of itiles)
    int h = bh & 7;
    int b = bh >> 3;
    int tid = threadIdx.x;
    int sub = tid >> 8;                   // 0/1: which itile
    int j = tid & 255;
    int i0b = ipair * 32;                 // block's 32 i-rows
    int i0 = i0b + sub * 16;              // this group's 16 rows

    __shared__ float2 sk[QDD][NN];        // 32 KB
    __shared__ float seX[QDD][32];        // 2 KB (SoA over 32 rows)
    __shared__ float seY[QDD][32];        // 2 KB
    __shared__ float sqeX[32];
    __shared__ float sqeY[32];

    v2f ar2[8], ai2[8];
#pragma unroll
    for (int rp = 0; rp < 8; ++rp) { ar2[rp] = (v2f)(0.f); ai2[rp] = (v2f)(0.f); }

    for (int m = 0; m < MM; ++m) {
        const float2* kk = E + (size_t)((((BB + b) * MM + m) * NHH + h) * QDD) * NN; // t=1
        const float2* e0 = E + (size_t)(((b * MM + m) * NHH + h) * QDD) * NN;        // t=0
        __syncthreads();
        for (int i2 = tid; i2 < QDD * NN; i2 += 512)
            sk[i2 >> 8][i2 & 255] = kk[i2];
        {
            int q = tid & 15;
            int r = tid >> 4;             // 0..31
            float2 e = e0[q * NN + i0b + r];
            seX[q][r] = e.x;
            seY[q][r] = e.y;
        }
        if (tid < 32) {
            float2 qe = QE[(size_t)((b * MM + m) * NHH + h) * NN + i0b + tid];
            sqeX[tid] = qe.x;
            sqeY[tid] = qe.y;
        }
        __syncthreads();

        // this thread's K column into registers
        float2 kreg[QDD];
#pragma unroll
        for (int q = 0; q < QDD; ++q) kreg[q] = sk[q][j];

#pragma unroll
        for (int q = 0; q < QDD; ++q) {
            v2f kx  = {kreg[q].x, kreg[q].x};
            v2f ky  = {kreg[q].y, kreg[q].y};
            v2f nkx = -kx;
#pragma unroll
            for (int rp = 0; rp < 8; ++rp) {
                v2f ex = *(const v2f*)&seX[q][sub * 16 + 2 * rp];  // group-uniform
                v2f ey = *(const v2f*)&seY[q][sub * 16 + 2 * rp];
                // ar[r] += e.x*k.x + e.y*k.y ; ai[r] += e.x*k.y - e.y*k.x
                ar2[rp] = PKFMA(ex, kx, PKFMA(ey, ky,  ar2[rp]));
                ai2[rp] = PKFMA(ex, ky, PKFMA(ey, nkx, ai2[rp]));
            }
        }

        // pe term: ar[r] += qe.x*p.x - qe.y*p.y ; ai[r] += qe.x*p.y + qe.y*p.x
#pragma unroll
        for (int rp = 0; rp < 8; ++rp) {
            float2 p0 = peIJ[(size_t)(m * NN + i0 + 2 * rp) * NN + j];     // coalesced
            float2 p1 = peIJ[(size_t)(m * NN + i0 + 2 * rp + 1) * NN + j];
            v2f px = {p0.x, p1.x}, py = {p0.y, p1.y};
            v2f qx = *(const v2f*)&sqeX[sub * 16 + 2 * rp];
            v2f qy = *(const v2f*)&sqeY[sub * 16 + 2 * rp];
            v2f nqy = -qy;
            ar2[rp] = PKFMA(px, qx, PKFMA(py, nqy, ar2[rp]));
            ai2[rp] = PKFMA(py, qx, PKFMA(px, qy,  ai2[rp]));
        }
    }
#pragma unroll
    for (int rp = 0; rp < 8; ++rp) {
        A[(size_t)(bh * NN + i0 + 2 * rp) * NN + j]     = make_float2(ar2[rp].x, ai2[rp].x);
        A[(size_t)(bh * NN + i0 + 2 * rp + 1) * NN + j] = make_float2(ar2[rp].y, ai2[rp].y);
    }
}

// ---------------------------------------------------------------------------
// Kernel 4: row softmax of |A|/4 over j; writes TRANSPOSED Aw:
//   AwT[(bh*N + j)*N + i]
// ---------------------------------------------------------------------------
__global__ void softmax_kernel(const float2* __restrict__ A, float* __restrict__ AwT) {
    int row = blockIdx.x;                 // (b*NHH+h)*NN + i
    int j = threadIdx.x;
    float2 a = A[(size_t)row * NN + j];
    float v = sqrtf(fmaf(a.x, a.x, a.y * a.y)) * 0.25f;

    __shared__ float smax[4];
    __shared__ float ssum[4];
    int lane = threadIdx.x & 63;
    int wid  = threadIdx.x >> 6;

    float mv = v;
#pragma unroll
    for (int off = 32; off > 0; off >>= 1) mv = fmaxf(mv, __shfl_xor(mv, off));
    if (lane == 0) smax[wid] = mv;
    __syncthreads();
    float mx = fmaxf(fmaxf(smax[0], smax[1]), fmaxf(smax[2], smax[3]));

    float e = expf(v - mx);
    float sv = e;
#pragma unroll
    for (int off = 32; off > 0; off >>= 1) sv += __shfl_xor(sv, off);
    if (lane == 0) ssum[wid] = sv;
    __syncthreads();
    float sum = ssum[0] + ssum[1] + ssum[2] + ssum[3];

    float aw = e / sum;
    int bh = row >> 8;
    int i  = row & 255;
    AwT[(size_t)(bh * NN + j) * NN + i] = aw;
}

// ---------------------------------------------------------------------------
// Kernel 5 (qh-split + XCD swizzle): 512 blocks = 64 idx x 8 xcd.
// ---------------------------------------------------------------------------
__global__ __launch_bounds__(512)
void res_kernel(const float2* __restrict__ E, const float* __restrict__ AwT,
                const float2* __restrict__ peT,
                const float* __restrict__ encr, const float* __restrict__ enci,
                float2* __restrict__ Res) {
    int bid = blockIdx.x;
    int xcd = bid & 7;
    int idx = bid >> 3;                   // 0..63
    int bh = xcd * 8 + (idx & 7);         // b*NHH+h
    int mqh = idx >> 3;                   // 0..7
    int m  = mqh >> 1;
    int qh = mqh & 1;
    int h = bh & 7;
    int b = bh >> 3;
    int i = threadIdx.x & 255;
    int g = threadIdx.x >> 8;             // j-half 0/1

    __shared__ float2 sv[8][NN];          // 16 KB: this qh's 8 V rows
    __shared__ float2 spA[NN][9];         // 18 KB: g=1 partials (8 acc + PA)
    __shared__ float2 senc[8];

    const float2* V = E + ((size_t)(((2 * BB + b) * MM + m) * NHH + h) * QDD + qh * 8) * NN;
    for (int i2 = threadIdx.x; i2 < 8 * NN; i2 += 512) sv[i2 >> 8][i2 & 255] = V[i2];
    if (threadIdx.x < 8) {
        int eb = ((MM + m) * NHH + h) * QDD + qh * 8 + threadIdx.x;   // enc[1,...]
        senc[threadIdx.x] = make_float2(encr[eb], enci[eb]);
    }
    __syncthreads();

    float accr[8], acci[8];
#pragma unroll
    for (int q = 0; q < 8; ++q) { accr[q] = 0.f; acci[q] = 0.f; }
    float par = 0.f, pai = 0.f;

    const float*  awp = AwT + (size_t)((b * NHH + h) * NN) * NN + i;
    const float2* pep = peT + (size_t)(m * NN) * NN + i;
    int j0 = g * (NN / 2);
    for (int j = j0; j < j0 + NN / 2; ++j) {
        float aw  = awp[(size_t)j * NN];      // coalesced over i
        float2 p  = pep[(size_t)j * NN];      // coalesced over i
        par = fmaf(p.x, aw, par);
        pai = fmaf(p.y, aw, pai);
#pragma unroll
        for (int q = 0; q < 8; ++q) {
            float2 vv = sv[q][j];             // wave-uniform -> broadcast
            accr[q] = fmaf(vv.x, aw, accr[q]);
            acci[q] = fmaf(vv.y, aw, acci[q]);
        }
    }

    if (g == 1) {
#pragma unroll
        for (int q = 0; q < 8; ++q) spA[i][q] = make_float2(accr[q], acci[q]);
        spA[i][8] = make_float2(par, pai);
    }
    __syncthreads();
    if (g == 0) {
#pragma unroll
        for (int q = 0; q < 8; ++q) {
            float2 o = spA[i][q];
            accr[q] += o.x; acci[q] += o.y;
        }
        float2 o = spA[i][8];
        par += o.x; pai += o.y;

        float2* rp = Res + ((size_t)((b * MM + m) * KO + h * QDD + qh * 8)) * NN + i;
#pragma unroll
        for (int q = 0; q < 8; ++q) {
            float2 e1 = senc[q];
            float rr = accr[q] + e1.x * par - e1.y * pai;
            float ri = acci[q] + e1.x * pai + e1.y * par;
            rp[(size_t)q * NN] = make_float2(rr, ri);
        }
    }
}

// ---------------------------------------------------------------------------
// Kernel 6 (DTILE=8 + XCD swizzle): out[b,m,D,n] = sum_k w_out*res.
// ---------------------------------------------------------------------------
__global__ void out_kernel(const float2* __restrict__ Res,
                           const float* __restrict__ wor, const float* __restrict__ woi,
                           float* __restrict__ out) {
    int bid = blockIdx.x;
    int xcd = bid & 7;
    int idx = bid >> 3;                   // 0..63
    int bm = xcd * 4 + (idx & 3);         // b*MM+m, 0..31
    int dt = idx >> 2;                    // 0..15
    int n = threadIdx.x;
    int D0 = dt * DTILE;
    int m = bm & 3;

    __shared__ float2 sw[DTILE][KO];      // 8 KB
    for (int i2 = threadIdx.x; i2 < DTILE * KO; i2 += 256) {
        int d = i2 >> 7, k = i2 & 127;
        int wb = (m * DD + D0 + d) * KO + k;
        sw[d][k] = make_float2(wor[wb], woi[wb]);
    }
    __syncthreads();

    const float2* rp = Res + (size_t)(bm * KO) * NN + n;
    float ar[DTILE], ai[DTILE];
#pragma unroll
    for (int d = 0; d < DTILE; ++d) { ar[d] = 0.f; ai[d] = 0.f; }

    for (int k = 0; k < KO; ++k) {
        float2 r = rp[(size_t)k * NN];    // coalesced
#pragma unroll
        for (int d = 0; d < DTILE; ++d) {
            float2 w = sw[d][k];          // broadcast
            ar[d] = fmaf(w.x, r.x, fmaf(-w.y, r.y, ar[d]));
            ai[d] = fmaf(w.x, r.y, fmaf( w.y, r.x, ai[d]));
        }
    }
#pragma unroll
    for (int d = 0; d < DTILE; ++d) {
        size_t ob = (size_t)(bm * DD + D0 + d) * NN + n;
        out[ob] = ar[d];
        out[(size_t)BB * MM * DD * NN + ob] = ai[d];
    }
}

// ---------------------------------------------------------------------------
extern "C" void kernel_launch(void* const* d_in, const int* in_sizes, int n_in,
                              void* d_out, int out_size, void* d_ws, size_t ws_size,
                              hipStream_t stream) {
    (void)in_sizes; (void)n_in; (void)out_size; (void)ws_size;

    const float* x_re   = (const float*)d_in[0];
    const float* x_im   = (const float*)d_in[1];
    const float* emb_re = (const float*)d_in[2];
    const float* emb_im = (const float*)d_in[3];
    const float* enc_re = (const float*)d_in[4];
    const float* enc_im = (const float*)d_in[5];
    const float* out_re = (const float*)d_in[6];
    const float* out_im = (const float*)d_in[7];
    float* out = (float*)d_out;

    // Workspace layout (floats). Total ~155.7 MB.
    float* ws = (float*)d_ws;
    size_t off = 0;
    float2* peIJ = (float2*)(ws + off); off += (size_t)MM * NN * NN * 2;          // 524288
    float2* peT  = (float2*)(ws + off); off += (size_t)MM * NN * NN * 2;          // 524288
    float2* E    = (float2*)(ws + off); off += (size_t)3 * BB * MM * NHH * QDD * NN * 2; // 25165824
    float2* QE   = (float2*)(ws + off); off += (size_t)BB * MM * NHH * NN * 2;    // 131072
    float2* A    = (float2*)(ws + off); off += (size_t)BB * NHH * NN * NN * 2;    // 8388608
    float*  AwT  = (float*)(ws + off);  off += (size_t)BB * NHH * NN * NN;        // 4194304
    float2* Res  = A;  // alias: A is dead after softmax (Res = 2097152 floats)

    // split-bf16 staging carved from the A region (17.5 MB of 32 MB); consumed
    // by e_mfma BEFORE a_kernel overwrites A — safe in-stream ordering.
    unsigned int* AbfHi = (unsigned int*)A;                       // 96*2048 uints
    unsigned int* AbfLo = AbfHi + (size_t)96 * QDD * DD;
    unsigned int* BreHi = AbfLo + (size_t)96 * QDD * DD;          // 32*256*128 each
    unsigned int* BreLo = BreHi + (size_t)32 * 256 * 128;
    unsigned int* BimHi = BreLo + (size_t)32 * 256 * 128;
    unsigned int* BimLo = BimHi + (size_t)32 * 256 * 128;

    pe_kernel<<<MM * NN, 256, 0, stream>>>(peIJ, peT);
    convA_kernel<<<96, 256, 0, stream>>>(emb_re, emb_im, AbfHi, AbfLo);
    convB_kernel<<<256, 256, 0, stream>>>(x_re, x_im, BreHi, BreLo, BimHi, BimLo);
    e_mfma_kernel<<<3 * BB * MM * NHH, 256, 0, stream>>>(
        (const unsigned short*)AbfHi, (const unsigned short*)AbfLo,
        (const unsigned short*)BreHi, (const unsigned short*)BreLo,
        (const unsigned short*)BimHi, (const unsigned short*)BimLo, E);
    qe_kernel<<<BB * MM * NHH, 256, 0, stream>>>(E, enc_re, enc_im, QE);
    a_kernel<<<BB * NHH * 8, 512, 0, stream>>>(E, QE, peIJ, A);
    softmax_kernel<<<BB * NHH * NN, 256, 0, stream>>>(A, AwT);
    res_kernel<<<BB * MM * NHH * 2, 512, 0, stream>>>(E, AwT, peT, enc_re, enc_im, Res);
    out_kernel<<<BB * MM * (DD / DTILE), 256, 0, stream>>>(Res, out_re, out_im, out);
}

// Round 29
// 163.566 us; speedup vs baseline: 1.2346x; 1.2346x over previous
//
#include <hip/hip_runtime.h>
#include <math.h>

// Problem constants (from reference)
#define BB   8      // batch
#define MM   4      // MAXM
#define DD   128    // DIM
#define NHH  8      // heads
#define QDD  16     // head dim
#define NN   256    // H*W
#define KO   128    // NH*QD
#define DTILE 8     // D-rows per out_kernel block

typedef float v2f __attribute__((ext_vector_type(2)));
#define PKFMA(a, b, c) __builtin_elementwise_fma((a), (b), (c))

typedef __attribute__((ext_vector_type(8))) short bf16x8;   // 8 bf16 (4 VGPR)
typedef __attribute__((ext_vector_type(4))) float f32x4;    // MFMA acc

__device__ inline unsigned short f2bf(float f) {            // RNE float->bf16
    union { float f; unsigned u; } v; v.f = f;
    unsigned r = v.u + 0x7FFF + ((v.u >> 16) & 1);
    return (unsigned short)(r >> 16);
}
__device__ inline float bf2f(unsigned short h) {
    union { unsigned u; float f; } v; v.u = ((unsigned)h) << 16;
    return v.f;
}
// split x = hi + lo (both bf16)
__device__ inline void bfsplit(float x, unsigned short& hi, unsigned short& lo) {
    hi = f2bf(x);
    lo = f2bf(x - bf2f(hi));
}
// Bre fragment (br | -bi<<16 per uint) -> Bim fragment (bi | br<<16)
__device__ inline bf16x8 derive_im(bf16x8 v) {
    union { bf16x8 v; unsigned u[4]; } in, out;
    in.v = v;
#pragma unroll
    for (int w = 0; w < 4; ++w)
        out.u[w] = ((in.u[w] >> 16) ^ 0x8000u) | (in.u[w] << 16);
    return out.v;
}

// ---------------------------------------------------------------------------
// Kernel 0 (trig-free): pe[m,i,j] = exp(i*m*theta) = ((dx+i*dy)/r)^m.
// ---------------------------------------------------------------------------
__global__ void pe_kernel(float2* __restrict__ peIJ, float2* __restrict__ peT) {
    int bid = blockIdx.x;           // m*N + i
    int m = bid >> 8;
    int i = bid & 255;
    int j = threadIdx.x;
    float dy = (float)((j >> 4) - (i >> 4));
    float dx = (float)((j & 15) - (i & 15));
    float r2 = dx * dx + dy * dy;
    float c1 = 1.f, s1 = 0.f;
    if (r2 > 0.f) {
        float rinv = rsqrtf(r2);
        c1 = dx * rinv; s1 = dy * rinv;
    }
    float c = 1.f, s = 0.f;
    for (int k = 0; k < m; ++k) {   // m is block-uniform (0..3)
        float nc = c * c1 - s * s1;
        s = c * s1 + s * c1;
        c = nc;
    }
    peIJ[(m * NN + i) * NN + j] = make_float2(c, s);
    peT[(m * NN + j) * NN + i] = make_float2(c, s);
}

// ---------------------------------------------------------------------------
// Kernel 1a: convA — emb -> A' split-bf16. uint idx = tmh*2048 + q*128 + D;
// low short = k=2D (ar), high short = k=2D+1 (ai).
// ---------------------------------------------------------------------------
__global__ void convA_kernel(const float* __restrict__ er, const float* __restrict__ ei,
                             unsigned int* __restrict__ AbfHi, unsigned int* __restrict__ AbfLo) {
    int tmh = blockIdx.x;                 // 0..95
    int base = tmh * QDD * DD;
#pragma unroll
    for (int it = 0; it < 8; ++it) {
        int idx = threadIdx.x + it * 256;  // q*128+D
        float ar = er[base + idx];
        float ai = ei[base + idx];
        unsigned short arh, arl, aih, ail;
        bfsplit(ar, arh, arl);
        bfsplit(ai, aih, ail);
        AbfHi[base + idx] = (unsigned int)arh | ((unsigned int)aih << 16);
        AbfLo[base + idx] = (unsigned int)arl | ((unsigned int)ail << 16);
    }
}

// ---------------------------------------------------------------------------
// Kernel 1b: convB — x -> split-bf16 Bre only (Bim derived in-register in
// e_mfma). k-fastest layout [32 bm][256 n][128 D]uints; [2D]=br, [2D+1]=-bi.
// ---------------------------------------------------------------------------
__global__ void convB_kernel(const float* __restrict__ xr, const float* __restrict__ xi,
                             unsigned int* __restrict__ BreHi, unsigned int* __restrict__ BreLo) {
    int bid = blockIdx.x;                 // 256 = 32 bm x 8 Dg
    int bm = bid >> 3;
    int Dg = bid & 7;
    int D0 = Dg * 16;
    int tid = threadIdx.x;

    __shared__ float sxr[16][257];
    __shared__ float sxi[16][257];

    const float* xrp = xr + (size_t)bm * DD * NN;
    const float* xip = xi + (size_t)bm * DD * NN;
#pragma unroll
    for (int it = 0; it < 16; ++it) {
        int i2 = tid + it * 256;
        int r = i2 >> 8, c = i2 & 255;
        sxr[r][c] = xrp[(size_t)(D0 + r) * NN + c];
        sxi[r][c] = xip[(size_t)(D0 + r) * NN + c];
    }
    __syncthreads();

    int n = tid;
    unsigned int reh[16], rel_[16];
#pragma unroll
    for (int d = 0; d < 16; ++d) {
        float br = sxr[d][n];
        float bi = sxi[d][n];
        unsigned short brh, brl, bih, bil;
        bfsplit(br, brh, brl);
        bfsplit(bi, bih, bil);
        reh[d]  = (unsigned int)brh | ((unsigned int)(bih ^ 0x8000) << 16);
        rel_[d] = (unsigned int)brl | ((unsigned int)(bil ^ 0x8000) << 16);
    }
    size_t ob = (size_t)bm * 32768 + (size_t)n * 128 + D0;
#pragma unroll
    for (int w = 0; w < 4; ++w) {
        ((uint4*)(BreHi + ob))[w] = make_uint4(reh[4*w], reh[4*w+1], reh[4*w+2], reh[4*w+3]);
        ((uint4*)(BreLo + ob))[w] = make_uint4(rel_[4*w], rel_[4*w+1], rel_[4*w+2], rel_[4*w+3]);
    }
}

// ---------------------------------------------------------------------------
// Kernel 1c (MFMA v2, t-merged): block = (pair, h) computes ALL 3 t planes.
// B fragments loaded once per (ks,nt) and reused by 3 t (18 MFMA / 2 loads);
// Bim derived in-register. 256 blocks = 1/CU; launch_bounds(256,1) frees
// VGPR for acc (96) + frags so loads pipeline under MFMA.
// ---------------------------------------------------------------------------
__global__ __launch_bounds__(256, 1)
void e_mfma_kernel(const unsigned short* __restrict__ AbfHi,
                   const unsigned short* __restrict__ AbfLo,
                   const unsigned short* __restrict__ BreHi,
                   const unsigned short* __restrict__ BreLo,
                   float2* __restrict__ E) {
    int bid = blockIdx.x;                 // 256 = 8 xcd x 32 idx
    int xcd = bid & 7;
    int idx = bid >> 3;                   // 0..31
    int pair = xcd * 4 + (idx & 3);       // b*MM+m (XCD-pinned B panels)
    int h = idx >> 2;                     // 0..7
    int b = pair >> 2, m = pair & 3;
    int tid = threadIdx.x;
    int wav = tid >> 6, lane = tid & 63;
    int lo = lane & 15, hi = lane >> 4;

    const unsigned short* AH[3];
    const unsigned short* AL[3];
#pragma unroll
    for (int t = 0; t < 3; ++t) {
        size_t aoff = ((size_t)((t * MM + m) * NHH + h)) * QDD * 256;
        AH[t] = AbfHi + aoff;
        AL[t] = AbfLo + aoff;
    }
    size_t boff = (size_t)pair * 256 * 256;
    const unsigned short* BrH = BreHi + boff;
    const unsigned short* BrL = BreLo + boff;

    f32x4 accRe[3][4], accIm[3][4];
#pragma unroll
    for (int t = 0; t < 3; ++t)
#pragma unroll
        for (int nt = 0; nt < 4; ++nt) {
            accRe[t][nt] = (f32x4)(0.f);
            accIm[t][nt] = (f32x4)(0.f);
        }

#pragma unroll
    for (int ks = 0; ks < 8; ++ks) {
        int k0 = ks * 32;
        int arow = lo * 256 + k0 + hi * 8;
        bf16x8 aH[3], aL[3];
#pragma unroll
        for (int t = 0; t < 3; ++t) {
            aH[t] = *(const bf16x8*)(AH[t] + arow);
            aL[t] = *(const bf16x8*)(AL[t] + arow);
        }
#pragma unroll
        for (int nt = 0; nt < 4; ++nt) {
            int n0 = (wav * 4 + nt) * 16;
            size_t brow = (size_t)(n0 + lo) * 256 + k0 + hi * 8;
            bf16x8 brh = *(const bf16x8*)(BrH + brow);
            bf16x8 brl = *(const bf16x8*)(BrL + brow);
            bf16x8 bih = derive_im(brh);
            bf16x8 bil = derive_im(brl);
#pragma unroll
            for (int t = 0; t < 3; ++t) {
                accRe[t][nt] = __builtin_amdgcn_mfma_f32_16x16x32_bf16(aH[t], brh, accRe[t][nt], 0, 0, 0);
                accRe[t][nt] = __builtin_amdgcn_mfma_f32_16x16x32_bf16(aH[t], brl, accRe[t][nt], 0, 0, 0);
                accRe[t][nt] = __builtin_amdgcn_mfma_f32_16x16x32_bf16(aL[t], brh, accRe[t][nt], 0, 0, 0);
                accIm[t][nt] = __builtin_amdgcn_mfma_f32_16x16x32_bf16(aH[t], bih, accIm[t][nt], 0, 0, 0);
                accIm[t][nt] = __builtin_amdgcn_mfma_f32_16x16x32_bf16(aH[t], bil, accIm[t][nt], 0, 0, 0);
                accIm[t][nt] = __builtin_amdgcn_mfma_f32_16x16x32_bf16(aL[t], bih, accIm[t][nt], 0, 0, 0);
            }
        }
    }

#pragma unroll
    for (int t = 0; t < 3; ++t) {
        size_t ebase = (size_t)((((t * BB + b) * MM + m) * NHH + h) * QDD) * NN;
#pragma unroll
        for (int nt = 0; nt < 4; ++nt) {
            int n0 = (wav * 4 + nt) * 16;
#pragma unroll
            for (int reg = 0; reg < 4; ++reg) {
                int q = hi * 4 + reg;
                E[ebase + (size_t)q * NN + n0 + lo] = make_float2(accRe[t][nt][reg], accIm[t][nt][reg]);
            }
        }
    }
}

// ---------------------------------------------------------------------------
// Kernel 2: QE[b,m,h,i] = sum_q conj(E0[b,m,h,q,i]) * enc0[m,h,q]
// ---------------------------------------------------------------------------
__global__ void qe_kernel(const float2* __restrict__ E,
                          const float* __restrict__ encr, const float* __restrict__ enci,
                          float2* __restrict__ QE) {
    int bid = blockIdx.x;                 // (b*MM+m)*NHH + h
    int i = threadIdx.x;
    const float2* e0 = E + (size_t)(bid) * QDD * NN;   // t=0 plane
    int h = bid & 7;
    int bm = bid >> 3;
    int m = bm & 3;
    int encbase = (m * NHH + h) * QDD;    // enc[0,m,h,0,q,0]
    float ar = 0.f, ai = 0.f;
#pragma unroll
    for (int q = 0; q < QDD; ++q) {
        float2 e = e0[q * NN + i];
        float cr = encr[encbase + q], ci = enci[encbase + q];
        // conj(e) * enc
        ar = fmaf(e.x, cr, fmaf( e.y, ci, ar));
        ai = fmaf(e.x, ci, fmaf(-e.y, cr, ai));
    }
    QE[(size_t)bid * NN + i] = make_float2(ar, ai);
}

// ---------------------------------------------------------------------------
// Kernel 3 (v4): A[b,h,i,j]; 512 thr = 2 itiles x 256 j; shared sk staging.
// ---------------------------------------------------------------------------
__global__ __launch_bounds__(512)
void a_kernel(const float2* __restrict__ E, const float2* __restrict__ QE,
              const float2* __restrict__ peIJ, float2* __restrict__ A) {
    int bid = blockIdx.x;                 // 512 blocks = 8 xcd x 64 idx
    int xcd = bid & 7;
    int idx = bid >> 3;                   // 0..63
    int bh = xcd * 8 + (idx & 7);         // b*NHH+h, 0..63
    int ipair = idx >> 3;                 // 0..7 (pair of itiles)
    int h = bh & 7;
    int b = bh >> 3;
    int tid = threadIdx.x;
    int sub = tid >> 8;                   // 0/1: which itile
    int j = tid & 255;
    int i0b = ipair * 32;                 // block's 32 i-rows
    int i0 = i0b + sub * 16;              // this group's 16 rows

    __shared__ float2 sk[QDD][NN];        // 32 KB
    __shared__ float seX[QDD][32];        // 2 KB (SoA over 32 rows)
    __shared__ float seY[QDD][32];        // 2 KB
    __shared__ float sqeX[32];
    __shared__ float sqeY[32];

    v2f ar2[8], ai2[8];
#pragma unroll
    for (int rp = 0; rp < 8; ++rp) { ar2[rp] = (v2f)(0.f); ai2[rp] = (v2f)(0.f); }

    for (int m = 0; m < MM; ++m) {
        const float2* kk = E + (size_t)((((BB + b) * MM + m) * NHH + h) * QDD) * NN; // t=1
        const float2* e0 = E + (size_t)(((b * MM + m) * NHH + h) * QDD) * NN;        // t=0
        __syncthreads();
        for (int i2 = tid; i2 < QDD * NN; i2 += 512)
            sk[i2 >> 8][i2 & 255] = kk[i2];
        {
            int q = tid & 15;
            int r = tid >> 4;             // 0..31
            float2 e = e0[q * NN + i0b + r];
            seX[q][r] = e.x;
            seY[q][r] = e.y;
        }
        if (tid < 32) {
            float2 qe = QE[(size_t)((b * MM + m) * NHH + h) * NN + i0b + tid];
            sqeX[tid] = qe.x;
            sqeY[tid] = qe.y;
        }
        __syncthreads();

        // this thread's K column into registers
        float2 kreg[QDD];
#pragma unroll
        for (int q = 0; q < QDD; ++q) kreg[q] = sk[q][j];

#pragma unroll
        for (int q = 0; q < QDD; ++q) {
            v2f kx  = {kreg[q].x, kreg[q].x};
            v2f ky  = {kreg[q].y, kreg[q].y};
            v2f nkx = -kx;
#pragma unroll
            for (int rp = 0; rp < 8; ++rp) {
                v2f ex = *(const v2f*)&seX[q][sub * 16 + 2 * rp];  // group-uniform
                v2f ey = *(const v2f*)&seY[q][sub * 16 + 2 * rp];
                // ar[r] += e.x*k.x + e.y*k.y ; ai[r] += e.x*k.y - e.y*k.x
                ar2[rp] = PKFMA(ex, kx, PKFMA(ey, ky,  ar2[rp]));
                ai2[rp] = PKFMA(ex, ky, PKFMA(ey, nkx, ai2[rp]));
            }
        }

        // pe term: ar[r] += qe.x*p.x - qe.y*p.y ; ai[r] += qe.x*p.y + qe.y*p.x
#pragma unroll
        for (int rp = 0; rp < 8; ++rp) {
            float2 p0 = peIJ[(size_t)(m * NN + i0 + 2 * rp) * NN + j];     // coalesced
            float2 p1 = peIJ[(size_t)(m * NN + i0 + 2 * rp + 1) * NN + j];
            v2f px = {p0.x, p1.x}, py = {p0.y, p1.y};
            v2f qx = *(const v2f*)&sqeX[sub * 16 + 2 * rp];
            v2f qy = *(const v2f*)&sqeY[sub * 16 + 2 * rp];
            v2f nqy = -qy;
            ar2[rp] = PKFMA(px, qx, PKFMA(py, nqy, ar2[rp]));
            ai2[rp] = PKFMA(py, qx, PKFMA(px, qy,  ai2[rp]));
        }
    }
#pragma unroll
    for (int rp = 0; rp < 8; ++rp) {
        A[(size_t)(bh * NN + i0 + 2 * rp) * NN + j]     = make_float2(ar2[rp].x, ai2[rp].x);
        A[(size_t)(bh * NN + i0 + 2 * rp + 1) * NN + j] = make_float2(ar2[rp].y, ai2[rp].y);
    }
}

// ---------------------------------------------------------------------------
// Kernel 4: row softmax of |A|/4 over j; writes TRANSPOSED Aw:
//   AwT[(bh*N + j)*N + i]
// ---------------------------------------------------------------------------
__global__ void softmax_kernel(const float2* __restrict__ A, float* __restrict__ AwT) {
    int row = blockIdx.x;                 // (b*NHH+h)*NN + i
    int j = threadIdx.x;
    float2 a = A[(size_t)row * NN + j];
    float v = sqrtf(fmaf(a.x, a.x, a.y * a.y)) * 0.25f;

    __shared__ float smax[4];
    __shared__ float ssum[4];
    int lane = threadIdx.x & 63;
    int wid  = threadIdx.x >> 6;

    float mv = v;
#pragma unroll
    for (int off = 32; off > 0; off >>= 1) mv = fmaxf(mv, __shfl_xor(mv, off));
    if (lane == 0) smax[wid] = mv;
    __syncthreads();
    float mx = fmaxf(fmaxf(smax[0], smax[1]), fmaxf(smax[2], smax[3]));

    float e = expf(v - mx);
    float sv = e;
#pragma unroll
    for (int off = 32; off > 0; off >>= 1) sv += __shfl_xor(sv, off);
    if (lane == 0) ssum[wid] = sv;
    __syncthreads();
    float sum = ssum[0] + ssum[1] + ssum[2] + ssum[3];

    float aw = e / sum;
    int bh = row >> 8;
    int i  = row & 255;
    AwT[(size_t)(bh * NN + j) * NN + i] = aw;
}

// ---------------------------------------------------------------------------
// Kernel 5 (qh-split + XCD swizzle): 512 blocks = 64 idx x 8 xcd.
// ---------------------------------------------------------------------------
__global__ __launch_bounds__(512)
void res_kernel(const float2* __restrict__ E, const float* __restrict__ AwT,
                const float2* __restrict__ peT,
                const float* __restrict__ encr, const float* __restrict__ enci,
                float2* __restrict__ Res) {
    int bid = blockIdx.x;
    int xcd = bid & 7;
    int idx = bid >> 3;                   // 0..63
    int bh = xcd * 8 + (idx & 7);         // b*NHH+h
    int mqh = idx >> 3;                   // 0..7
    int m  = mqh >> 1;
    int qh = mqh & 1;
    int h = bh & 7;
    int b = bh >> 3;
    int i = threadIdx.x & 255;
    int g = threadIdx.x >> 8;             // j-half 0/1

    __shared__ float2 sv[8][NN];          // 16 KB: this qh's 8 V rows
    __shared__ float2 spA[NN][9];         // 18 KB: g=1 partials (8 acc + PA)
    __shared__ float2 senc[8];

    const float2* V = E + ((size_t)(((2 * BB + b) * MM + m) * NHH + h) * QDD + qh * 8) * NN;
    for (int i2 = threadIdx.x; i2 < 8 * NN; i2 += 512) sv[i2 >> 8][i2 & 255] = V[i2];
    if (threadIdx.x < 8) {
        int eb = ((MM + m) * NHH + h) * QDD + qh * 8 + threadIdx.x;   // enc[1,...]
        senc[threadIdx.x] = make_float2(encr[eb], enci[eb]);
    }
    __syncthreads();

    float accr[8], acci[8];
#pragma unroll
    for (int q = 0; q < 8; ++q) { accr[q] = 0.f; acci[q] = 0.f; }
    float par = 0.f, pai = 0.f;

    const float*  awp = AwT + (size_t)((b * NHH + h) * NN) * NN + i;
    const float2* pep = peT + (size_t)(m * NN) * NN + i;
    int j0 = g * (NN / 2);
    for (int j = j0; j < j0 + NN / 2; ++j) {
        float aw  = awp[(size_t)j * NN];      // coalesced over i
        float2 p  = pep[(size_t)j * NN];      // coalesced over i
        par = fmaf(p.x, aw, par);
        pai = fmaf(p.y, aw, pai);
#pragma unroll
        for (int q = 0; q < 8; ++q) {
            float2 vv = sv[q][j];             // wave-uniform -> broadcast
            accr[q] = fmaf(vv.x, aw, accr[q]);
            acci[q] = fmaf(vv.y, aw, acci[q]);
        }
    }

    if (g == 1) {
#pragma unroll
        for (int q = 0; q < 8; ++q) spA[i][q] = make_float2(accr[q], acci[q]);
        spA[i][8] = make_float2(par, pai);
    }
    __syncthreads();
    if (g == 0) {
#pragma unroll
        for (int q = 0; q < 8; ++q) {
            float2 o = spA[i][q];
            accr[q] += o.x; acci[q] += o.y;
        }
        float2 o = spA[i][8];
        par += o.x; pai += o.y;

        float2* rp = Res + ((size_t)((b * MM + m) * KO + h * QDD + qh * 8)) * NN + i;
#pragma unroll
        for (int q = 0; q < 8; ++q) {
            float2 e1 = senc[q];
            float rr = accr[q] + e1.x * par - e1.y * pai;
            float ri = acci[q] + e1.x * pai + e1.y * par;
            rp[(size_t)q * NN] = make_float2(rr, ri);
        }
    }
}

// ---------------------------------------------------------------------------
// Kernel 6 (DTILE=8 + XCD swizzle): out[b,m,D,n] = sum_k w_out*res.
// ---------------------------------------------------------------------------
__global__ void out_kernel(const float2* __restrict__ Res,
                           const float* __restrict__ wor, const float* __restrict__ woi,
                           float* __restrict__ out) {
    int bid = blockIdx.x;
    int xcd = bid & 7;
    int idx = bid >> 3;                   // 0..63
    int bm = xcd * 4 + (idx & 3);         // b*MM+m, 0..31
    int dt = idx >> 2;                    // 0..15
    int n = threadIdx.x;
    int D0 = dt * DTILE;
    int m = bm & 3;

    __shared__ float2 sw[DTILE][KO];      // 8 KB
    for (int i2 = threadIdx.x; i2 < DTILE * KO; i2 += 256) {
        int d = i2 >> 7, k = i2 & 127;
        int wb = (m * DD + D0 + d) * KO + k;
        sw[d][k] = make_float2(wor[wb], woi[wb]);
    }
    __syncthreads();

    const float2* rp = Res + (size_t)(bm * KO) * NN + n;
    float ar[DTILE], ai[DTILE];
#pragma unroll
    for (int d = 0; d < DTILE; ++d) { ar[d] = 0.f; ai[d] = 0.f; }

    for (int k = 0; k < KO; ++k) {
        float2 r = rp[(size_t)k * NN];    // coalesced
#pragma unroll
        for (int d = 0; d < DTILE; ++d) {
            float2 w = sw[d][k];          // broadcast
            ar[d] = fmaf(w.x, r.x, fmaf(-w.y, r.y, ar[d]));
            ai[d] = fmaf(w.x, r.y, fmaf( w.y, r.x, ai[d]));
        }
    }
#pragma unroll
    for (int d = 0; d < DTILE; ++d) {
        size_t ob = (size_t)(bm * DD + D0 + d) * NN + n;
        out[ob] = ar[d];
        out[(size_t)BB * MM * DD * NN + ob] = ai[d];
    }
}

// ---------------------------------------------------------------------------
extern "C" void kernel_launch(void* const* d_in, const int* in_sizes, int n_in,
                              void* d_out, int out_size, void* d_ws, size_t ws_size,
                              hipStream_t stream) {
    (void)in_sizes; (void)n_in; (void)out_size; (void)ws_size;

    const float* x_re   = (const float*)d_in[0];
    const float* x_im   = (const float*)d_in[1];
    const float* emb_re = (const float*)d_in[2];
    const float* emb_im = (const float*)d_in[3];
    const float* enc_re = (const float*)d_in[4];
    const float* enc_im = (const float*)d_in[5];
    const float* out_re = (const float*)d_in[6];
    const float* out_im = (const float*)d_in[7];
    float* out = (float*)d_out;

    // Workspace layout (floats). Total ~155.7 MB.
    float* ws = (float*)d_ws;
    size_t off = 0;
    float2* peIJ = (float2*)(ws + off); off += (size_t)MM * NN * NN * 2;          // 524288
    float2* peT  = (float2*)(ws + off); off += (size_t)MM * NN * NN * 2;          // 524288
    float2* E    = (float2*)(ws + off); off += (size_t)3 * BB * MM * NHH * QDD * NN * 2; // 25165824
    float2* QE   = (float2*)(ws + off); off += (size_t)BB * MM * NHH * NN * 2;    // 131072
    float2* A    = (float2*)(ws + off); off += (size_t)BB * NHH * NN * NN * 2;    // 8388608
    float*  AwT  = (float*)(ws + off);  off += (size_t)BB * NHH * NN * NN;        // 4194304
    float2* Res  = A;  // alias: A is dead after softmax (Res = 2097152 floats)

    // split-bf16 staging carved from the A region (~9.5 MB of 32 MB);
    // consumed by e_mfma BEFORE a_kernel overwrites A.
    unsigned int* AbfHi = (unsigned int*)A;                       // 96*2048 uints
    unsigned int* AbfLo = AbfHi + (size_t)96 * QDD * DD;
    unsigned int* BreHi = AbfLo + (size_t)96 * QDD * DD;          // 32*256*128 each
    unsigned int* BreLo = BreHi + (size_t)32 * 256 * 128;

    pe_kernel<<<MM * NN, 256, 0, stream>>>(peIJ, peT);
    convA_kernel<<<96, 256, 0, stream>>>(emb_re, emb_im, AbfHi, AbfLo);
    convB_kernel<<<256, 256, 0, stream>>>(x_re, x_im, BreHi, BreLo);
    e_mfma_kernel<<<256, 256, 0, stream>>>(
        (const unsigned short*)AbfHi, (const unsigned short*)AbfLo,
        (const unsigned short*)BreHi, (const unsigned short*)BreLo, E);
    qe_kernel<<<BB * MM * NHH, 256, 0, stream>>>(E, enc_re, enc_im, QE);
    a_kernel<<<BB * NHH * 8, 512, 0, stream>>>(E, QE, peIJ, A);
    softmax_kernel<<<BB * NHH * NN, 256, 0, stream>>>(A, AwT);
    res_kernel<<<BB * MM * NHH * 2, 512, 0, stream>>>(E, AwT, peT, enc_re, enc_im, Res);
    out_kernel<<<BB * MM * (DD / DTILE), 256, 0, stream>>>(Res, out_re, out_im, out);
}